// Round 6
// baseline (207.999 us; speedup 1.0000x reference)
//
#include <hip/hip_runtime.h>

// ConvAttention collapse:
//   softmax_j(Aq[i]+Ak[j]+ba) == softmax_j(Ak_linear[j])   (i-terms & biases cancel)
//   out[i] = Wv * (sum_j sm[j] * x[j]) + bv                (identical for all i)
// Only x, Wk, Wv, bv, Wa[:,C:] are used.

#define HW    9216      // 96*96
#define HDIM  96
#define WDIM  96
#define CDIM  128
#define LDIM  16

__device__ __forceinline__ void fma4(float4& a, const float4& x, const float4& s) {
    a.x += x.x * s.x; a.y += x.y * s.y; a.z += x.z * s.z; a.w += x.w * s.w;
}
__device__ __forceinline__ void axpy4(float4& o, float w, const float4& v) {
    o.x += w * v.x; o.y += w * v.y; o.z += w * v.z; o.w += w * v.w;
}

// ---------------- K1: effective conv weight -----------------------------
// weff[c'][tap] = sum_d Wk[d][c'] * Wa[(128+d)][tap]   (tap = kh*5+kw)
__global__ void k_weff(const float* __restrict__ Wk, const float* __restrict__ Wa,
                       float* __restrict__ weff) {
    int idx = blockIdx.x * 256 + threadIdx.x;
    if (idx >= 128 * 25) return;
    int cp = idx / 25, tap = idx % 25;
    float s = 0.f;
    for (int c = 0; c < 128; ++c)
        s += Wk[c * 128 + cp] * Wa[(128 + c) * 25 + tap];
    weff[idx] = s;
}

// ---------------- K2: 5x5 conv of x with weff, register/L1 version -------
// grid (16 j, 6 rowtiles of 16, 8 cgroups of 16ch), block 192.
// Thread owns 2 output rows x 4 cols; no LDS tile, no barrier in hot loop.
__global__ __launch_bounds__(192) void k_conv(const float* __restrict__ x,
                                              const float* __restrict__ weff,
                                              float* __restrict__ part) {
    const int j  = blockIdx.x;
    const int rt = blockIdx.y;
    const int g  = blockIdx.z;
    const int tid = threadIdx.x;

    __shared__ float wsm[16 * 25];
    for (int i = tid; i < 16 * 25; i += 192) wsm[i] = weff[g * 16 * 25 + i];
    __syncthreads();

    const int q  = tid % 24;           // col quad: cols 4q..4q+3
    const int rg = tid / 24;           // 0..7
    const int r0 = rt * 16 + rg * 2;   // 2 output rows: r0, r0+1
    const int cb = q * 4 - 4;          // leftmost loaded col (quad 0)

    const bool cok0 = (q > 0);         // quad at cb
    const bool cok2 = (q < 23);        // quad at cb+8

    float4 acc0 = make_float4(0.f, 0.f, 0.f, 0.f);
    float4 acc1 = make_float4(0.f, 0.f, 0.f, 0.f);
    const float4 z = make_float4(0.f, 0.f, 0.f, 0.f);

    for (int ch = 0; ch < 16; ++ch) {
        const float* plane = x + (size_t)(j * CDIM + g * 16 + ch) * HW;
        const float* wc = wsm + ch * 25;
        #pragma unroll
        for (int wr = 0; wr < 6; ++wr) {
            const int row = r0 - 2 + wr;
            const bool rowok = (row >= 0) && (row < HDIM);
            const float* rp = plane + row * WDIM + cb;
            float4 a = (rowok && cok0) ? *(const float4*)(rp)     : z;
            float4 b = (rowok        ) ? *(const float4*)(rp + 4) : z;
            float4 c = (rowok && cok2) ? *(const float4*)(rp + 8) : z;
            float win[12] = {a.x, a.y, a.z, a.w, b.x, b.y, b.z, b.w,
                             c.x, c.y, c.z, c.w};
            if (wr <= 4) {                       // output row r0, kh = wr
                const float* wk = wc + wr * 5;
                #pragma unroll
                for (int kw = 0; kw < 5; ++kw) {
                    float w = wk[kw];
                    acc0.x += w * win[kw + 2]; acc0.y += w * win[kw + 3];
                    acc0.z += w * win[kw + 4]; acc0.w += w * win[kw + 5];
                }
            }
            if (wr >= 1) {                       // output row r0+1, kh = wr-1
                const float* wk = wc + (wr - 1) * 5;
                #pragma unroll
                for (int kw = 0; kw < 5; ++kw) {
                    float w = wk[kw];
                    acc1.x += w * win[kw + 2]; acc1.y += w * win[kw + 3];
                    acc1.z += w * win[kw + 4]; acc1.w += w * win[kw + 5];
                }
            }
        }
    }
    float* pr = part + (size_t)(g * 16 + j) * HW;
    *(float4*)(pr + r0 * WDIM + q * 4)       = acc0;
    *(float4*)(pr + (r0 + 1) * WDIM + q * 4) = acc1;
}

// ---------------- K3: combine partials + softmax over j ------------------
__global__ void k_softmax(const float* __restrict__ part, float* __restrict__ sm) {
    int px = blockIdx.x * 256 + threadIdx.x;   // 9216 total
    float s[16];
    #pragma unroll
    for (int jj = 0; jj < 16; ++jj) s[jj] = 0.f;
    for (int g = 0; g < 8; ++g) {
        #pragma unroll
        for (int jj = 0; jj < 16; ++jj)
            s[jj] += part[(size_t)(g * 16 + jj) * HW + px];
    }
    float m = s[0];
    #pragma unroll
    for (int jj = 1; jj < 16; ++jj) m = fmaxf(m, s[jj]);
    float tot = 0.f;
    #pragma unroll
    for (int jj = 0; jj < 16; ++jj) { s[jj] = __expf(s[jj] - m); tot += s[jj]; }
    float inv = 1.f / tot;
    #pragma unroll
    for (int jj = 0; jj < 16; ++jj) sm[(size_t)jj * HW + px] = s[jj] * inv;
}

// ---------------- K4: transpose Wv -> wvt[cp][c] --------------------------
__global__ void k_wvt(const float* __restrict__ Wv, float* __restrict__ wvt) {
    int idx = blockIdx.x * 256 + threadIdx.x;   // 16384
    int c = idx >> 7, cp = idx & 127;
    wvt[cp * 128 + c] = Wv[idx];
}

// ---------------- K5: fused xbar + matvec + broadcast store ---------------
// grid 288 blocks x 256 thr; block owns 32 px.
// Phase 1: tile[cp][0..31] = sum_j sm[j]*x[j][cp]  (x read exactly once)
// Phase 2: out[i][c] = Wv*tile + bv, written for all 16 i.
__global__ __launch_bounds__(256) void k_out(const float* __restrict__ x,
                                             const float* __restrict__ sm,
                                             const float* __restrict__ wvt,
                                             const float* __restrict__ bv,
                                             float* __restrict__ out) {
    __shared__ float smt[16 * 32];
    __shared__ float tile[128 * 32];
    const int tid = threadIdx.x;
    const int px0 = blockIdx.x * 32;

    if (tid < 128) {
        int j = tid >> 3, qq = tid & 7;
        *(float4*)(smt + j * 32 + qq * 4) =
            *(const float4*)(sm + (size_t)j * HW + px0 + qq * 4);
    }
    __syncthreads();

    // phase 1: weighted average of x over j, into LDS tile
    {
        const int cp = tid >> 1, h = tid & 1;       // 16-px half per thread
        const float* xb = x + (size_t)cp * HW + px0 + h * 16;
        float4 a0 = make_float4(0.f, 0.f, 0.f, 0.f), a1 = a0, a2 = a0, a3 = a0;
        #pragma unroll
        for (int j = 0; j < 16; ++j) {
            const float* xp = xb + (size_t)j * CDIM * HW;
            float4 x0 = *(const float4*)(xp);
            float4 x1 = *(const float4*)(xp + 4);
            float4 x2 = *(const float4*)(xp + 8);
            float4 x3 = *(const float4*)(xp + 12);
            const float* sp = smt + j * 32 + h * 16;
            fma4(a0, x0, *(const float4*)(sp));
            fma4(a1, x1, *(const float4*)(sp + 4));
            fma4(a2, x2, *(const float4*)(sp + 8));
            fma4(a3, x3, *(const float4*)(sp + 12));
        }
        float* tp = tile + cp * 32 + h * 16;
        *(float4*)(tp)      = a0;
        *(float4*)(tp + 4)  = a1;
        *(float4*)(tp + 8)  = a2;
        *(float4*)(tp + 12) = a3;
    }
    __syncthreads();

    // phase 2: 128x128 matvec on the tile
    const int q  = tid & 7;           // px quad within tile
    const int cg = tid >> 3;          // 0..31
    const int c0 = cg * 4;            // 4 output channels
    float4 o0 = make_float4(0.f, 0.f, 0.f, 0.f), o1 = o0, o2 = o0, o3 = o0;
    #pragma unroll 4
    for (int cp = 0; cp < 128; ++cp) {
        float4 xv = *(const float4*)(tile + cp * 32 + q * 4);
        float4 wv = *(const float4*)(wvt + cp * 128 + c0);
        axpy4(o0, wv.x, xv);
        axpy4(o1, wv.y, xv);
        axpy4(o2, wv.z, xv);
        axpy4(o3, wv.w, xv);
    }
    float b0 = bv[c0], b1 = bv[c0 + 1], b2 = bv[c0 + 2], b3 = bv[c0 + 3];
    o0.x += b0; o0.y += b0; o0.z += b0; o0.w += b0;
    o1.x += b1; o1.y += b1; o1.z += b1; o1.w += b1;
    o2.x += b2; o2.y += b2; o2.z += b2; o2.w += b2;
    o3.x += b3; o3.y += b3; o3.z += b3; o3.w += b3;

    for (int i = 0; i < 16; ++i) {
        float* ob = out + (size_t)(i * CDIM + c0) * HW + px0 + q * 4;
        *(float4*)(ob)          = o0;
        *(float4*)(ob + HW)     = o1;
        *(float4*)(ob + 2 * HW) = o2;
        *(float4*)(ob + 3 * HW) = o3;
    }
}

extern "C" void kernel_launch(void* const* d_in, const int* in_sizes, int n_in,
                              void* d_out, int out_size, void* d_ws, size_t ws_size,
                              hipStream_t stream) {
    const float* x  = (const float*)d_in[0];
    const float* Wk = (const float*)d_in[3];
    const float* Wv = (const float*)d_in[5];
    const float* bv = (const float*)d_in[6];
    const float* Wa = (const float*)d_in[7];
    float* out = (float*)d_out;

    char* ws = (char*)d_ws;
    float* weff = (float*)(ws);                          // 12.8 KB (pad to 16 KB)
    float* part = (float*)(ws + 16384);                  // 8*16*9216*4 = 4.72 MB
    float* sm   = (float*)(ws + 16384 + 4718592);        // 16*9216*4  = 590 KB
    float* wvt  = part;   // reuse: part dead after k_softmax; k_wvt runs after it

    k_weff   <<<13,              256, 0, stream>>>(Wk, Wa, weff);
    k_conv   <<<dim3(16, 6, 8),  192, 0, stream>>>(x, weff, part);
    k_softmax<<<36,              256, 0, stream>>>(part, sm);
    k_wvt    <<<64,              256, 0, stream>>>(Wv, wvt);
    k_out    <<<288,             256, 0, stream>>>(x, sm, wvt, bv, out);
}

// Round 7
// 116.201 us; speedup vs baseline: 1.7900x; 1.7900x over previous
//
#include <hip/hip_runtime.h>

// ConvAttention collapse:
//   softmax_j(Aq[i]+Ak[j]+ba) == softmax_j(Ak_linear[j])   (i-terms & biases cancel)
//   out[i] = Wv * (sum_j sm[j] * x[j]) + bv                (identical for all i)
// Ak via z-refactor: z[j,t,hw] = sum_c weff[c,t] x[j,c,hw]  (per-pixel GEMV)
//                    Ak[j,px]  = sum_t z[j,t,px+off(t)]     (shifted sum)

#define HW    9216      // 96*96
#define HDIM  96
#define WDIM  96
#define CDIM  128
#define LDIM  16

__device__ __forceinline__ void fma4(float4& a, const float4& x, const float4& s) {
    a.x += x.x * s.x; a.y += x.y * s.y; a.z += x.z * s.z; a.w += x.w * s.w;
}
__device__ __forceinline__ void axpy4(float4& o, float w, const float4& v) {
    o.x += w * v.x; o.y += w * v.y; o.z += w * v.z; o.w += w * v.w;
}

// ---------------- K0: prep — weff (blocks 0..12) + Wv transpose (13..76) --
// weff[c'][tap] = sum_c Wk[c][c'] * Wa[(128+c)][tap]
__global__ void k_prep(const float* __restrict__ Wk, const float* __restrict__ Wa,
                       const float* __restrict__ Wv,
                       float* __restrict__ weff, float* __restrict__ wvt) {
    const int b = blockIdx.x;
    if (b < 13) {
        int idx = b * 256 + threadIdx.x;
        if (idx < 128 * 25) {
            int cp = idx / 25, tap = idx % 25;
            float s = 0.f;
            for (int c = 0; c < 128; ++c)
                s += Wk[c * 128 + cp] * Wa[(128 + c) * 25 + tap];
            weff[idx] = s;
        }
    } else {
        int idx = (b - 13) * 256 + threadIdx.x;        // 0..16383
        wvt[(idx & 127) * 128 + (idx >> 7)] = Wv[idx]; // wvt[c'][c] = Wv[c][c']
    }
}

// ---------------- K1: z[j][t][hw] = sum_c weff[c][t] * x[j][c][hw] ---------
// grid (36, 16), 256 thr, 1 px/thread. Coalesced stride-1 x loads; weights
// broadcast from LDS (padded rows, 16B-aligned for ds_read_b128).
__global__ __launch_bounds__(256) void k_z(const float* __restrict__ x,
                                           const float* __restrict__ weff,
                                           float* __restrict__ z) {
    __shared__ float wsm[128 * 28];
    const int tid = threadIdx.x;
    for (int i = tid; i < 128 * 25; i += 256)
        wsm[(i / 25) * 28 + (i % 25)] = weff[i];
    __syncthreads();

    const int j  = blockIdx.y;
    const int hw = blockIdx.x * 256 + tid;
    const float* xb = x + (size_t)j * CDIM * HW + hw;

    float acc[25];
    #pragma unroll
    for (int t = 0; t < 25; ++t) acc[t] = 0.f;

    #pragma unroll 2
    for (int c = 0; c < 128; ++c) {
        float xv = xb[(size_t)c * HW];
        const float* wr = wsm + c * 28;
        #pragma unroll
        for (int t = 0; t < 25; ++t) acc[t] = fmaf(wr[t], xv, acc[t]);
    }
    float* zb = z + (size_t)j * 25 * HW + hw;
    #pragma unroll
    for (int t = 0; t < 25; ++t) zb[(size_t)t * HW] = acc[t];
}

// ---------------- K2: ak[j][px] = sum_t z[j][t][px + off(t)] (bounded) -----
__global__ __launch_bounds__(256) void k_ak(const float* __restrict__ z,
                                            float* __restrict__ ak) {
    const int j  = blockIdx.y;
    const int px = blockIdx.x * 256 + threadIdx.x;
    const int h = px / WDIM, w = px % WDIM;
    const float* zb = z + (size_t)j * 25 * HW + px;
    float s = 0.f;
    #pragma unroll
    for (int kh = 0; kh < 5; ++kh) {
        const bool rok = (unsigned)(h + kh - 2) < (unsigned)HDIM;
        #pragma unroll
        for (int kw = 0; kw < 5; ++kw) {
            const bool ok = rok && ((unsigned)(w + kw - 2) < (unsigned)WDIM);
            const int t = kh * 5 + kw;
            s += ok ? zb[t * HW + (kh - 2) * WDIM + (kw - 2)] : 0.f;
        }
    }
    ak[(size_t)j * HW + px] = s;
}

// ---------------- fallback conv (round-5 proven, small-ws path) -----------
__global__ __launch_bounds__(192) void k_conv(const float* __restrict__ x,
                                              const float* __restrict__ weff,
                                              float* __restrict__ part) {
    const int j  = blockIdx.x;
    const int rt = blockIdx.y;
    const int g  = blockIdx.z;
    const int c0 = g * 16;
    __shared__ float tile[36 * 104];
    __shared__ float wsm[16 * 25];
    const int tid = threadIdx.x;
    for (int i = tid; i < 16 * 25; i += 192) wsm[i] = weff[c0 * 25 + i];
    const int cq = tid % 24;
    const int rg = tid / 24;
    const int r0 = rg * 4;
    const int rowbase = rt * 32;

    float4 acc[4];
    acc[0] = acc[1] = acc[2] = acc[3] = make_float4(0.f, 0.f, 0.f, 0.f);

    for (int ch = 0; ch < 16; ++ch) {
        const float* xc = x + (size_t)(j * CDIM + c0 + ch) * HW;
        __syncthreads();
        for (int idx = tid; idx < 36 * 26; idx += 192) {
            int r = idx / 26, q = idx % 26;
            int gr = rowbase - 2 + r;
            int gc = q * 4 - 4;
            float4 v = make_float4(0.f, 0.f, 0.f, 0.f);
            if (gr >= 0 && gr < HDIM && gc >= 0 && gc < WDIM)
                v = *(const float4*)(xc + gr * WDIM + gc);
            *(float4*)(tile + r * 104 + q * 4) = v;
        }
        __syncthreads();
        const float* wc = wsm + ch * 25;
        for (int rr = 0; rr < 8; ++rr) {
            const float* trow = tile + (r0 + rr) * 104 + cq * 4;
            float4 a  = *(const float4*)(trow);
            float4 b  = *(const float4*)(trow + 4);
            float4 c4 = *(const float4*)(trow + 8);
            float win[12] = {a.x, a.y, a.z, a.w, b.x, b.y, b.z, b.w,
                             c4.x, c4.y, c4.z, c4.w};
            #pragma unroll
            for (int orow = 0; orow < 4; ++orow) {
                int kh = rr - orow;
                if (kh < 0 || kh > 4) continue;
                #pragma unroll
                for (int kw = 0; kw < 5; ++kw) {
                    float w = wc[kh * 5 + kw];
                    acc[orow].x += w * win[kw + 2];
                    acc[orow].y += w * win[kw + 3];
                    acc[orow].z += w * win[kw + 4];
                    acc[orow].w += w * win[kw + 5];
                }
            }
        }
    }
    float* pr = part + (size_t)(g * 16 + j) * HW;
    #pragma unroll
    for (int orow = 0; orow < 4; ++orow) {
        int row = rowbase + r0 + orow;
        *(float4*)(pr + row * WDIM + cq * 4) = acc[orow];
    }
}

__global__ void k_combine(const float* __restrict__ part, float* __restrict__ ak) {
    const int j  = blockIdx.y;
    const int px = blockIdx.x * 256 + threadIdx.x;
    float s = 0.f;
    #pragma unroll
    for (int g = 0; g < 8; ++g) s += part[(size_t)(g * 16 + j) * HW + px];
    ak[(size_t)j * HW + px] = s;
}

// ---------------- K3: fused softmax + xbar + matvec + broadcast store ------
// grid 576 x 256; block owns 16 px.
__global__ __launch_bounds__(256) void k_out(const float* __restrict__ x,
                                             const float* __restrict__ ak,
                                             const float* __restrict__ wvt,
                                             const float* __restrict__ bv,
                                             float* __restrict__ out) {
    __shared__ float akt[256];        // [j][p]
    __shared__ float minv[32];        // m[p] | inv[p]
    __shared__ float smt[256];        // sm[j][p]
    __shared__ float tile[128 * 16];  // xbar[cp][p]
    const int tid = threadIdx.x;
    const int px0 = blockIdx.x * 16;
    const int p   = tid & 15;

    // phase 0: softmax over j for this block's 16 px
    akt[tid] = ak[(size_t)(tid >> 4) * HW + px0 + p];
    __syncthreads();
    if (tid < 16) {
        float m = -1e30f;
        #pragma unroll
        for (int jj = 0; jj < 16; ++jj) m = fmaxf(m, akt[jj * 16 + tid]);
        float tot = 0.f;
        #pragma unroll
        for (int jj = 0; jj < 16; ++jj) tot += __expf(akt[jj * 16 + tid] - m);
        minv[tid]      = m;
        minv[16 + tid] = 1.f / tot;
    }
    __syncthreads();
    smt[tid] = __expf(akt[tid] - minv[p]) * minv[16 + p];
    __syncthreads();

    // phase 1: tile[cp][0..15] = sum_j smt[j]*x[j][cp]
    {
        const int cp = tid >> 1, h = tid & 1;
        const float* xb = x + (size_t)cp * HW + px0 + h * 8;
        float4 a0 = make_float4(0.f, 0.f, 0.f, 0.f), a1 = a0;
        #pragma unroll
        for (int j = 0; j < 16; ++j) {
            const float* xp = xb + (size_t)j * CDIM * HW;
            float4 x0 = *(const float4*)(xp);
            float4 x1 = *(const float4*)(xp + 4);
            const float* sp = smt + j * 16 + h * 8;
            fma4(a0, x0, *(const float4*)(sp));
            fma4(a1, x1, *(const float4*)(sp + 4));
        }
        float* tp = tile + cp * 16 + h * 8;
        *(float4*)(tp)     = a0;
        *(float4*)(tp + 4) = a1;
    }
    __syncthreads();

    // phase 2: 128x128 matvec; thread owns 2 channels x 4 px
    const int q  = tid & 3;
    const int c0 = (tid >> 2) * 2;
    float4 o0 = make_float4(0.f, 0.f, 0.f, 0.f), o1 = o0;
    #pragma unroll 4
    for (int cp = 0; cp < 128; ++cp) {
        float4 xv = *(const float4*)(tile + cp * 16 + q * 4);
        float2 wv = *(const float2*)(wvt + cp * 128 + c0);
        axpy4(o0, wv.x, xv);
        axpy4(o1, wv.y, xv);
    }
    float b0 = bv[c0], b1 = bv[c0 + 1];
    o0.x += b0; o0.y += b0; o0.z += b0; o0.w += b0;
    o1.x += b1; o1.y += b1; o1.z += b1; o1.w += b1;

    // phase 3: broadcast store to all 16 identical output frames
    for (int i = 0; i < 16; ++i) {
        float* ob = out + (size_t)(i * CDIM + c0) * HW + px0 + q * 4;
        *(float4*)(ob)      = o0;
        *(float4*)(ob + HW) = o1;
    }
}

extern "C" void kernel_launch(void* const* d_in, const int* in_sizes, int n_in,
                              void* d_out, int out_size, void* d_ws, size_t ws_size,
                              hipStream_t stream) {
    const float* x  = (const float*)d_in[0];
    const float* Wk = (const float*)d_in[3];
    const float* Wv = (const float*)d_in[5];
    const float* bv = (const float*)d_in[6];
    const float* Wa = (const float*)d_in[7];
    float* out = (float*)d_out;

    char* ws = (char*)d_ws;
    float* weff = (float*)(ws);             // 12.8 KB
    float* wvt  = (float*)(ws + 16384);     // 64 KB, ends 81920

    k_prep<<<77, 256, 0, stream>>>(Wk, Wa, Wv, weff, wvt);

    const size_t Z_BYTES    = (size_t)16 * 25 * HW * 4;   // 14.75 MB
    const size_t AK_BYTES   = (size_t)16 * HW * 4;        // 590 KB
    const size_t NEED_BIG   = 81920 + Z_BYTES + AK_BYTES; // 15.4 MB

    if (ws_size >= NEED_BIG) {
        float* z   = (float*)(ws + 81920);
        float* akb = (float*)(ws + 81920 + Z_BYTES);
        k_z <<<dim3(36, 16), 256, 0, stream>>>(x, weff, z);
        k_ak<<<dim3(36, 16), 256, 0, stream>>>(z, akb);
        k_out<<<576, 256, 0, stream>>>(x, akb, wvt, bv, out);
    } else {
        float* part = (float*)(ws + 81920);                // 4.72 MB
        float* akb  = (float*)(ws + 81920 + 4718592);      // 590 KB
        k_conv   <<<dim3(16, 3, 8), 192, 0, stream>>>(x, weff, part);
        k_combine<<<dim3(36, 16),   256, 0, stream>>>(part, akb);
        k_out    <<<576,            256, 0, stream>>>(x, akb, wvt, bv, out);
    }
}

// Round 8
// 81.486 us; speedup vs baseline: 2.5526x; 1.4260x over previous
//
#include <hip/hip_runtime.h>

// ConvAttention collapse:
//   softmax_j(Aq[i]+Ak[j]+ba) == softmax_j(Ak_linear[j])   (i-terms & biases cancel)
//   out[i] = Wv * (sum_j sm[j] * x[j]) + bv                (identical for all i)
// Pipeline: k_prep -> k_z (per-px 25x128 GEMV) -> k_ak (tap shift-sum)
//           -> k_xbar (in-thread softmax + weighted avg of x)
//           -> k_mat (128x128 matvec + 16x broadcast store, XCD-swizzled)

#define HW    9216      // 96*96
#define HDIM  96
#define WDIM  96
#define CDIM  128

__device__ __forceinline__ void fma4(float4& a, const float4& x, const float4& s) {
    a.x += x.x * s.x; a.y += x.y * s.y; a.z += x.z * s.z; a.w += x.w * s.w;
}
__device__ __forceinline__ void axpy4(float4& o, float w, const float4& v) {
    o.x += w * v.x; o.y += w * v.y; o.z += w * v.z; o.w += w * v.w;
}

// ---------------- K0: prep — weff (blocks 0..12) + Wv transpose (13..76) --
__global__ void k_prep(const float* __restrict__ Wk, const float* __restrict__ Wa,
                       const float* __restrict__ Wv,
                       float* __restrict__ weff, float* __restrict__ wvt) {
    const int b = blockIdx.x;
    if (b < 13) {
        int idx = b * 256 + threadIdx.x;
        if (idx < 128 * 25) {
            int cp = idx / 25, tap = idx % 25;
            float s = 0.f;
            for (int c = 0; c < 128; ++c)
                s += Wk[c * 128 + cp] * Wa[(128 + c) * 25 + tap];
            weff[idx] = s;
        }
    } else {
        int idx = (b - 13) * 256 + threadIdx.x;        // 0..16383
        wvt[(idx & 127) * 128 + (idx >> 7)] = Wv[idx]; // wvt[c'][c] = Wv[c][c']
    }
}

// ---------------- K1: z[j][t][hw] = sum_c weff[c][t] * x[j][c][hw] ---------
__global__ __launch_bounds__(256) void k_z(const float* __restrict__ x,
                                           const float* __restrict__ weff,
                                           float* __restrict__ z) {
    __shared__ float wsm[128 * 28];
    const int tid = threadIdx.x;
    for (int i = tid; i < 128 * 25; i += 256)
        wsm[(i / 25) * 28 + (i % 25)] = weff[i];
    __syncthreads();

    const int j  = blockIdx.y;
    const int hw = blockIdx.x * 256 + tid;
    const float* xb = x + (size_t)j * CDIM * HW + hw;

    float acc[25];
    #pragma unroll
    for (int t = 0; t < 25; ++t) acc[t] = 0.f;

    #pragma unroll 4
    for (int c = 0; c < 128; ++c) {
        float xv = xb[(size_t)c * HW];
        const float* wr = wsm + c * 28;
        #pragma unroll
        for (int t = 0; t < 25; ++t) acc[t] = fmaf(wr[t], xv, acc[t]);
    }
    float* zb = z + (size_t)j * 25 * HW + hw;
    #pragma unroll
    for (int t = 0; t < 25; ++t) zb[(size_t)t * HW] = acc[t];
}

// ---------------- K2: ak[j][px] = sum_t z[j][t][px + off(t)] (bounded) -----
__global__ __launch_bounds__(256) void k_ak(const float* __restrict__ z,
                                            float* __restrict__ ak) {
    const int j  = blockIdx.y;
    const int px = blockIdx.x * 256 + threadIdx.x;
    const int h = px / WDIM, w = px % WDIM;
    const float* zb = z + (size_t)j * 25 * HW + px;
    float s = 0.f;
    #pragma unroll
    for (int kh = 0; kh < 5; ++kh) {
        const bool rok = (unsigned)(h + kh - 2) < (unsigned)HDIM;
        #pragma unroll
        for (int kw = 0; kw < 5; ++kw) {
            const bool ok = rok && ((unsigned)(w + kw - 2) < (unsigned)WDIM);
            const int t = kh * 5 + kw;
            s += ok ? zb[t * HW + (kh - 2) * WDIM + (kw - 2)] : 0.f;
        }
    }
    ak[(size_t)j * HW + px] = s;
}

// ---------------- fallback conv path (small-ws; proven round 5) ------------
__global__ __launch_bounds__(192) void k_conv(const float* __restrict__ x,
                                              const float* __restrict__ weff,
                                              float* __restrict__ part) {
    const int j  = blockIdx.x;
    const int rt = blockIdx.y;
    const int g  = blockIdx.z;
    const int c0 = g * 16;
    __shared__ float tile[36 * 104];
    __shared__ float wsm[16 * 25];
    const int tid = threadIdx.x;
    for (int i = tid; i < 16 * 25; i += 192) wsm[i] = weff[c0 * 25 + i];
    const int cq = tid % 24;
    const int rg = tid / 24;
    const int r0 = rg * 4;
    const int rowbase = rt * 32;

    float4 acc[4];
    acc[0] = acc[1] = acc[2] = acc[3] = make_float4(0.f, 0.f, 0.f, 0.f);

    for (int ch = 0; ch < 16; ++ch) {
        const float* xc = x + (size_t)(j * CDIM + c0 + ch) * HW;
        __syncthreads();
        for (int idx = tid; idx < 36 * 26; idx += 192) {
            int r = idx / 26, q = idx % 26;
            int gr = rowbase - 2 + r;
            int gc = q * 4 - 4;
            float4 v = make_float4(0.f, 0.f, 0.f, 0.f);
            if (gr >= 0 && gr < HDIM && gc >= 0 && gc < WDIM)
                v = *(const float4*)(xc + gr * WDIM + gc);
            *(float4*)(tile + r * 104 + q * 4) = v;
        }
        __syncthreads();
        const float* wc = wsm + ch * 25;
        for (int rr = 0; rr < 8; ++rr) {
            const float* trow = tile + (r0 + rr) * 104 + cq * 4;
            float4 a  = *(const float4*)(trow);
            float4 b  = *(const float4*)(trow + 4);
            float4 c4 = *(const float4*)(trow + 8);
            float win[12] = {a.x, a.y, a.z, a.w, b.x, b.y, b.z, b.w,
                             c4.x, c4.y, c4.z, c4.w};
            #pragma unroll
            for (int orow = 0; orow < 4; ++orow) {
                int kh = rr - orow;
                if (kh < 0 || kh > 4) continue;
                #pragma unroll
                for (int kw = 0; kw < 5; ++kw) {
                    float w = wc[kh * 5 + kw];
                    acc[orow].x += w * win[kw + 2];
                    acc[orow].y += w * win[kw + 3];
                    acc[orow].z += w * win[kw + 4];
                    acc[orow].w += w * win[kw + 5];
                }
            }
        }
    }
    float* pr = part + (size_t)(g * 16 + j) * HW;
    #pragma unroll
    for (int orow = 0; orow < 4; ++orow) {
        int row = rowbase + r0 + orow;
        *(float4*)(pr + row * WDIM + cq * 4) = acc[orow];
    }
}

__global__ void k_combine(const float* __restrict__ part, float* __restrict__ ak) {
    const int j  = blockIdx.y;
    const int px = blockIdx.x * 256 + threadIdx.x;
    float s = 0.f;
    #pragma unroll
    for (int g = 0; g < 8; ++g) s += part[(size_t)(g * 16 + j) * HW + px];
    ak[(size_t)j * HW + px] = s;
}

// ---------------- K3: xbar[cp][px] = sum_j softmax_j(ak)[px] * x[j][cp][px] -
// grid 1152: cp = b/9, block spans 1024 contiguous px of one cp-plane.
// Softmax over j recomputed per thread from ak (L2-resident, ~free).
__global__ __launch_bounds__(256) void k_xbar(const float* __restrict__ x,
                                              const float* __restrict__ ak,
                                              float* __restrict__ xbar) {
    const int b  = blockIdx.x;
    const int cp = b / 9;
    const int px = (b % 9) * 1024 + threadIdx.x * 4;

    float4 av[16];
    #pragma unroll
    for (int j = 0; j < 16; ++j)
        av[j] = *(const float4*)(ak + (size_t)j * HW + px);

    float4 m = av[0];
    #pragma unroll
    for (int j = 1; j < 16; ++j) {
        m.x = fmaxf(m.x, av[j].x); m.y = fmaxf(m.y, av[j].y);
        m.z = fmaxf(m.z, av[j].z); m.w = fmaxf(m.w, av[j].w);
    }
    float4 tot = make_float4(0.f, 0.f, 0.f, 0.f);
    #pragma unroll
    for (int j = 0; j < 16; ++j) {
        av[j].x = __expf(av[j].x - m.x); av[j].y = __expf(av[j].y - m.y);
        av[j].z = __expf(av[j].z - m.z); av[j].w = __expf(av[j].w - m.w);
        tot.x += av[j].x; tot.y += av[j].y; tot.z += av[j].z; tot.w += av[j].w;
    }
    float4 inv = make_float4(1.f / tot.x, 1.f / tot.y, 1.f / tot.z, 1.f / tot.w);

    float4 acc = make_float4(0.f, 0.f, 0.f, 0.f);
    #pragma unroll
    for (int j = 0; j < 16; ++j) {
        float4 xv = *(const float4*)(x + (size_t)(j * CDIM + cp) * HW + px);
        fma4(acc, xv, av[j]);
    }
    acc.x *= inv.x; acc.y *= inv.y; acc.z *= inv.z; acc.w *= inv.w;
    *(float4*)(xbar + (size_t)cp * HW + px) = acc;
}

// ---------------- K4: out[i][c][px] = Wv*xbar + bv, 16x broadcast ----------
// 576 blocks, XCD-chunk swizzle so px-adjacent tiles share an XCD (write-half
// merging in L2). Stages xbar[128][16] in LDS (8 KB, broadcast reads).
__global__ __launch_bounds__(256) void k_mat(const float* __restrict__ xbar,
                                             const float* __restrict__ wvt,
                                             const float* __restrict__ bv,
                                             float* __restrict__ out) {
    __shared__ float lx[128 * 16];
    const int b    = blockIdx.x;
    const int tile = (b & 7) * 72 + (b >> 3);   // 576 = 8 * 72
    const int px0  = tile * 16;
    const int tid  = threadIdx.x;

    #pragma unroll
    for (int i = 0; i < 2; ++i) {
        int lin = tid + i * 256;                // 0..511
        int cp = lin >> 2, q = lin & 3;
        *(float4*)(lx + cp * 16 + q * 4) =
            *(const float4*)(xbar + (size_t)cp * HW + px0 + q * 4);
    }
    __syncthreads();

    const int q  = tid & 3;
    const int c0 = (tid >> 2) * 2;
    float4 o0 = make_float4(0.f, 0.f, 0.f, 0.f), o1 = o0;
    #pragma unroll 4
    for (int cp = 0; cp < 128; ++cp) {
        float4 xv = *(const float4*)(lx + cp * 16 + q * 4);
        float2 wv = *(const float2*)(wvt + cp * 128 + c0);
        axpy4(o0, wv.x, xv);
        axpy4(o1, wv.y, xv);
    }
    float b0 = bv[c0], b1 = bv[c0 + 1];
    o0.x += b0; o0.y += b0; o0.z += b0; o0.w += b0;
    o1.x += b1; o1.y += b1; o1.z += b1; o1.w += b1;

    for (int i = 0; i < 16; ++i) {
        float* ob = out + (size_t)(i * CDIM + c0) * HW + px0 + q * 4;
        *(float4*)(ob)      = o0;
        *(float4*)(ob + HW) = o1;
    }
}

extern "C" void kernel_launch(void* const* d_in, const int* in_sizes, int n_in,
                              void* d_out, int out_size, void* d_ws, size_t ws_size,
                              hipStream_t stream) {
    const float* x  = (const float*)d_in[0];
    const float* Wk = (const float*)d_in[3];
    const float* Wv = (const float*)d_in[5];
    const float* bv = (const float*)d_in[6];
    const float* Wa = (const float*)d_in[7];
    float* out = (float*)d_out;

    char* ws = (char*)d_ws;
    float* weff = (float*)(ws);             // 12.8 KB
    float* wvt  = (float*)(ws + 16384);     // 64 KB, ends 81920

    k_prep<<<77, 256, 0, stream>>>(Wk, Wa, Wv, weff, wvt);

    const size_t Z_BYTES  = (size_t)16 * 25 * HW * 4;   // 14.75 MB
    const size_t AK_BYTES = (size_t)16 * HW * 4;        // 590 KB
    const size_t NEED_BIG = 81920 + Z_BYTES + AK_BYTES; // 15.4 MB (proven fits)

    if (ws_size >= NEED_BIG) {
        float* z    = (float*)(ws + 81920);
        float* akb  = (float*)(ws + 81920 + Z_BYTES);
        float* xb   = (float*)(ws + 81920);             // overlay: z dead after k_ak
        k_z   <<<dim3(36, 16), 256, 0, stream>>>(x, weff, z);
        k_ak  <<<dim3(36, 16), 256, 0, stream>>>(z, akb);
        k_xbar<<<1152,         256, 0, stream>>>(x, akb, xb);
        k_mat <<<576,          256, 0, stream>>>(xb, wvt, bv, out);
    } else {
        float* part = (float*)(ws + 81920);             // 4.72 MB
        float* akb  = (float*)(ws + 81920 + 4718592);   // 590 KB
        float* xb   = (float*)(ws + 81920);             // overlay: part dead
        k_conv   <<<dim3(16, 3, 8), 192, 0, stream>>>(x, weff, part);
        k_combine<<<dim3(36, 16),   256, 0, stream>>>(part, akb);
        k_xbar   <<<1152,           256, 0, stream>>>(x, akb, xb);
        k_mat    <<<576,            256, 0, stream>>>(xb, wvt, bv, out);
    }
}